// Round 4
// baseline (471.724 us; speedup 1.0000x reference)
//
#include <hip/hip_runtime.h>

#define B_ 64
#define S_ 1024
#define NT 48
#define DM 512
#define TT 50

__device__ __forceinline__ float rl(float v, int lane) {
  return __int_as_float(__builtin_amdgcn_readlane(__float_as_int(v), lane));
}

// ---------------- K1: tag_vec = F @ W^T / sqrt(512) ----------------
__global__ __launch_bounds__(256) void k_tagvec(const float* __restrict__ F,
                                                const float* __restrict__ Wm,
                                                float* __restrict__ out) {
  __shared__ float fs[128][68];
  __shared__ float wsh[48][68];
  const int t = threadIdx.x;
  const int rowBase = blockIdx.x * 128;
  const int jg = t & 3;
  const int rq = t >> 2;
  const int r0 = rq * 2, r1 = r0 + 1;
  float acc0[12];
  float acc1[12];
#pragma unroll
  for (int q = 0; q < 12; ++q) { acc0[q] = 0.f; acc1[q] = 0.f; }
  for (int kc = 0; kc < DM; kc += 64) {
    __syncthreads();
#pragma unroll
    for (int i2 = 0; i2 < 8; ++i2) {
      int f = t + i2 * 256;
      int row = f >> 4, kk = f & 15;
      float4 v = *(const float4*)(F + (size_t)(rowBase + row) * DM + kc + kk * 4);
      *(float4*)&fs[row][kk * 4] = v;
    }
#pragma unroll
    for (int i2 = 0; i2 < 3; ++i2) {
      int f = t + i2 * 256;
      int row = f >> 4, kk = f & 15;
      float4 v = *(const float4*)(Wm + (size_t)row * DM + kc + kk * 4);
      *(float4*)&wsh[row][kk * 4] = v;
    }
    __syncthreads();
#pragma unroll 4
    for (int k4 = 0; k4 < 16; ++k4) {
      float4 a0 = *(const float4*)&fs[r0][k4 * 4];
      float4 a1 = *(const float4*)&fs[r1][k4 * 4];
#pragma unroll
      for (int jj = 0; jj < 12; ++jj) {
        float4 w = *(const float4*)&wsh[jg * 12 + jj][k4 * 4];
        acc0[jj] += a0.x * w.x + a0.y * w.y + a0.z * w.z + a0.w * w.w;
        acc1[jj] += a1.x * w.x + a1.y * w.y + a1.z * w.z + a1.w * w.w;
      }
    }
  }
  const float sc = 0.044194173824159216f;
  size_t base0 = (size_t)(rowBase + r0) * NT + jg * 12;
  size_t base1 = (size_t)(rowBase + r1) * NT + jg * 12;
#pragma unroll
  for (int q = 0; q < 3; ++q) {
    float4 o0 = make_float4(acc0[q*4]*sc, acc0[q*4+1]*sc, acc0[q*4+2]*sc, acc0[q*4+3]*sc);
    float4 o1 = make_float4(acc1[q*4]*sc, acc1[q*4+1]*sc, acc1[q*4+2]*sc, acc1[q*4+3]*sc);
    *(float4*)(out + base0 + q*4) = o0;
    *(float4*)(out + base1 + q*4) = o1;
  }
}

// ---------------- K2: gold-path score per batch ----------------
__global__ __launch_bounds__(256) void k_score(const float* __restrict__ tg,
                                               const int* __restrict__ y,
                                               const unsigned char* __restrict__ mask,
                                               const float* __restrict__ trans,
                                               float* __restrict__ scoreOut) {
  const int b = blockIdx.x, t = threadIdx.x;
  const int* yb = y + (size_t)b * S_;
  const unsigned char* mbp = mask + (size_t)b * S_;
  float part = 0.f;
  int cnt = 0;
  for (int s = t; s < S_; s += 256) {
    int ys = yb[s];
    int ms = mbp[s];
    float bm = ms ? 0.f : 1.f;
    int yy = ms ? 0 : ys;
    part += tg[((size_t)b * S_ + s) * NT + yy] * bm;
    if (s >= 1) part += trans[yb[s - 1] * TT + ys] * bm;
    cnt += ms ? 1 : 0;
  }
  for (int d = 1; d < 64; d <<= 1) {
    part += __shfl_xor(part, d);
    cnt += __shfl_xor(cnt, d);
  }
  __shared__ float pw[4];
  __shared__ int cw[4];
  int wid = t >> 6;
  if ((t & 63) == 0) { pw[wid] = part; cw[wid] = cnt; }
  __syncthreads();
  if (t == 0) {
    float tot = pw[0] + pw[1] + pw[2] + pw[3];
    int c = cw[0] + cw[1] + cw[2] + cw[3];
    int L = S_ - 1 - c;
    tot += trans[NT * TT + yb[0]];
    tot += trans[yb[L] * TT + (NT + 1)];
    scoreOut[b] = tot;
  }
}

// ---------------- K3: single-wave serial scans ----------------
// __launch_bounds__(64, 1): 1 wave/EU minimum -> VGPR cap 512, so Ecol/Tcol
// stay register-resident (round-3's 52-VGPR build re-loaded them from L2
// every step = the 816 cyc/step).
__global__ __launch_bounds__(64, 1) void k_scan(const float* __restrict__ tg,
                                                const unsigned char* __restrict__ mask,
                                                const float* __restrict__ trans,
                                                const float* __restrict__ score,
                                                float* __restrict__ Mbuf,
                                                int* __restrict__ nowbuf,
                                                float* __restrict__ out) {
  __shared__ float bmL[S_ + 4];
  __shared__ float rbuf[256];

  const int t = threadIdx.x;
  const bool isV = blockIdx.x >= B_;
  const int b = isV ? (blockIdx.x - B_) : blockIdx.x;
  const int jc = (t < NT) ? t : (NT - 1);
  const float* tgb = tg + (size_t)b * S_ * NT;

  int cnt = 0;
  for (int m = t; m < S_; m += 64) {
    unsigned char mv = mask[(size_t)b * S_ + m];
    bmL[m] = mv ? 0.f : 1.f;
    cnt += mv ? 1 : 0;
  }
  if (t < 4) bmL[S_ + t] = 0.f;
#pragma unroll
  for (int d = 1; d < 64; d <<= 1) cnt += __shfl_xor(cnt, d);
  const int L = S_ - 1 - cnt;
  __syncthreads();

  if (!isV) {
    // ---------- forward, linear domain, 8 independent fma chains ----------
    float Ecol[NT];
#pragma unroll
    for (int i = 0; i < NT; ++i) Ecol[i] = __expf(trans[i * TT + jc]);
    float p = __expf(trans[NT * TT + jc]);  // exp(start_j)
    float eA = tgb[jc];
    float eB = tgb[NT + jc];
    float eC = tgb[2 * NT + jc];
    float m0r = bmL[0], m1r = bmL[1];
    for (int s = 0; s < S_; ++s) {
      float pe = p * __expf(eA * m0r);
      int m1b = __builtin_amdgcn_readfirstlane(__float_as_int(m1r));
      float Z;
      if (m1b != 0) {
        float z[8];
#pragma unroll
        for (int c = 0; c < 8; ++c) z[c] = rl(pe, 6 * c) * Ecol[6 * c];
#pragma unroll
        for (int k = 1; k < 6; ++k) {
#pragma unroll
          for (int c = 0; c < 8; ++c)
            z[c] = fmaf(rl(pe, 6 * c + k), Ecol[6 * c + k], z[c]);
        }
        Z = ((z[0] + z[1]) + (z[2] + z[3])) + ((z[4] + z[5]) + (z[6] + z[7]));
      } else {
        float vv = (t < NT) ? pe : 0.f;
#pragma unroll
        for (int d = 1; d < 64; d <<= 1) vv += __shfl_xor(vv, d);
        Z = vv;
      }
      p = Z;
      if ((s & 3) == 3) {
        float M = p;
#pragma unroll
        for (int d = 1; d < 64; d <<= 1) M = fmaxf(M, __shfl_xor(M, d));
        float r = __builtin_amdgcn_rcpf(M);  // we log the actual r later: exact
        p *= r;
        if (t == 0) rbuf[s >> 2] = r;
      }
      eA = eB; eB = eC;
      int s3 = (s + 3 < S_) ? (s + 3) : (S_ - 1);
      eC = tgb[(size_t)s3 * NT + jc];
      m0r = m1r;
      m1r = bmL[s + 2];
    }
    float ls = 0.f;
#pragma unroll
    for (int k = 0; k < 4; ++k) ls += __logf(rbuf[t + 64 * k]);
#pragma unroll
    for (int d = 1; d < 64; d <<= 1) ls += __shfl_xor(ls, d);
    float v = (t < NT) ? p * __expf(trans[t * TT + (NT + 1)]) : 0.f;
#pragma unroll
    for (int d = 1; d < 64; d <<= 1) v += __shfl_xor(v, d);
    if (t == 0) out[b] = __logf(v) - ls - score[b];
  } else {
    // ---------- Viterbi value pass, 8 independent max chains ----------
    float Tcol[NT];
#pragma unroll
    for (int i = 0; i < NT; ++i) Tcol[i] = trans[i * TT + jc];
    float* Mb = Mbuf + (size_t)b * S_ * NT;
    float best = trans[NT * TT + jc] + tgb[jc];
    float fin = best;  // valid if L==0
    float eA = tgb[NT + jc];
    float eB = tgb[2 * NT + jc];
    float eC = tgb[3 * NT + jc];
    for (int s = 1; s < S_; ++s) {
      float mA[8];
#pragma unroll
      for (int c = 0; c < 8; ++c) mA[c] = rl(best, 6 * c) + Tcol[6 * c];
#pragma unroll
      for (int k = 1; k < 6; ++k) {
#pragma unroll
        for (int c = 0; c < 8; ++c)
          mA[c] = fmaxf(mA[c], rl(best, 6 * c + k) + Tcol[6 * c + k]);
      }
      float M = fmaxf(fmaxf(fmaxf(mA[0], mA[1]), fmaxf(mA[2], mA[3])),
                      fmaxf(fmaxf(mA[4], mA[5]), fmaxf(mA[6], mA[7])));
      Mb[(size_t)s * NT + jc] = M;  // dup writes from idle lanes: same value
      float bnew = M + eA;
      fin = (s == L) ? bnew : fin;
      best = bnew;
      eA = eB; eB = eC;
      int s3 = (s + 3 < S_) ? (s + 3) : (S_ - 1);
      eC = tgb[(size_t)s3 * NT + jc];
    }
    float v = (t < NT) ? (fin + trans[t * TT + (NT + 1)]) : -3.0e38f;
    float M = v;
#pragma unroll
    for (int d = 1; d < 64; d <<= 1) M = fmaxf(M, __shfl_xor(M, d));
    unsigned long long ball = __ballot(v == M);
    int now0 = __ffsll(ball) - 1;
    if (t == 0) nowbuf[b] = now0;
  }
}

// ---------------- K4: parallel argmax recompute (bit-exact replay) ----------------
__global__ __launch_bounds__(256) void k_idx(const float* __restrict__ tg,
                                             const float* __restrict__ Mbuf,
                                             const float* __restrict__ trans,
                                             unsigned char* __restrict__ idxbuf) {
  __shared__ float TshT[NT][NT];  // TshT[j][i] = trans[i][j]
  const int t = threadIdx.x;
  const int b = blockIdx.x;
  for (int k = t; k < NT * NT; k += 256) {
    int i = k / NT, j = k - i * NT;
    TshT[j][i] = trans[i * TT + j];
  }
  __syncthreads();
  const int s = blockIdx.y * 128 + (t >> 1);
  const int jh = (t & 1) * 24;
  if (s < 1) return;
  const float* tgb = tg + (size_t)b * S_ * NT;
  const float* Mb = Mbuf + (size_t)b * S_ * NT;
  float bprev[NT];
  if (s == 1) {
#pragma unroll
    for (int i = 0; i < NT; ++i) bprev[i] = trans[NT * TT + i] + tgb[i];
  } else {
#pragma unroll
    for (int i = 0; i < NT; ++i)
      bprev[i] = Mb[(size_t)(s - 1) * NT + i] + tgb[(size_t)(s - 1) * NT + i];
  }
  unsigned char* ob = idxbuf + ((size_t)b * S_ + s) * NT + jh;
#pragma unroll 4
  for (int jj = 0; jj < 24; ++jj) {
    int j = jh + jj;
    float M = Mb[(size_t)s * NT + j];
    int idx = 0;
#pragma unroll
    for (int i = NT - 1; i >= 0; --i) {
      float cc = bprev[i] + TshT[j][i];
      idx = (cc == M) ? i : idx;
    }
    ob[jj] = (unsigned char)idx;
  }
}

// ---------------- K5: backtrack via chunked pointer jumping ----------------
__global__ __launch_bounds__(1024) void k_btrack(const unsigned char* __restrict__ idxbuf,
                                                 const unsigned char* __restrict__ mask,
                                                 const int* __restrict__ nowbuf,
                                                 float* __restrict__ out) {
  __shared__ unsigned char idxL[S_][NT];
  __shared__ unsigned char mapc[16][NT];
  __shared__ int ELs[16];
  __shared__ int cnt_sh;
  const int t = threadIdx.x;
  const int b = blockIdx.x;
  if (t == 0) cnt_sh = 0;
  __syncthreads();
  {
    const unsigned int* src = (const unsigned int*)(idxbuf + (size_t)b * S_ * NT);
    unsigned int* dst = (unsigned int*)&idxL[t][0];
#pragma unroll
    for (int k = 0; k < 12; ++k) dst[k] = src[(size_t)t * 12 + k];
  }
  int mv = mask[(size_t)b * S_ + t] ? 1 : 0;
  unsigned long long bal = __ballot(mv);
  int wcnt = __popcll(bal);
  if ((t & 63) == 0 && wcnt) atomicAdd(&cnt_sh, wcnt);
  __syncthreads();
  const int L = S_ - 1 - cnt_sh;
  const int now0 = nowbuf[b];
  if (t < 16 * NT) {
    const int c = t / NT;
    const int g = t - c * NT;
    int cur = g;
    const int top = (c == 15) ? (S_ - 1) : (c + 1) * 64;
    const int base = c * 64;
    for (int m = top; m > base; --m) {
      if (m <= L) cur = idxL[m][cur];
    }
    mapc[c][g] = (unsigned char)cur;
  }
  __syncthreads();
  if (t == 0) {
    int e = now0;
    ELs[15] = e;
    for (int c2 = 15; c2 >= 1; --c2) {
      e = mapc[c2][e];
      ELs[c2 - 1] = e;
    }
  }
  __syncthreads();
  float* pathOut = out + B_ + (size_t)b * S_;
  if (t < 16) {
    const int c = t;
    const int top = (c == 15) ? (S_ - 1) : (c + 1) * 64;
    const int base = c * 64;
    int cu = ELs[c];
    for (int m = top; m > base; --m) {
      if (m <= L) cu = idxL[m][cu];
      int pos = m - 1;
      pathOut[pos] = (pos > L) ? -1.0f : (float)cu;
    }
  }
  if (t == 0) pathOut[S_ - 1] = (L == S_ - 1) ? (float)now0 : -1.0f;
}

extern "C" void kernel_launch(void* const* d_in, const int* in_sizes, int n_in,
                              void* d_out, int out_size, void* d_ws, size_t ws_size,
                              hipStream_t stream) {
  const float* F = (const float*)d_in[0];
  const int* y = (const int*)d_in[1];
  const unsigned char* mask = (const unsigned char*)d_in[2];
  const float* Wm = (const float*)d_in[3];
  const float* trans = (const float*)d_in[4];
  float* out = (float*)d_out;

  const size_t NTG = (size_t)B_ * S_ * NT;
  float* tg = (float*)d_ws;
  float* score = tg + NTG;
  float* Mbuf = score + 64;
  int* nowbuf = (int*)(Mbuf + NTG);
  unsigned char* idxbuf = (unsigned char*)(nowbuf + 64);

  k_tagvec<<<dim3((B_ * S_) / 128), dim3(256), 0, stream>>>(F, Wm, tg);
  k_score<<<dim3(B_), dim3(256), 0, stream>>>(tg, y, mask, trans, score);
  k_scan<<<dim3(2 * B_), dim3(64), 0, stream>>>(tg, mask, trans, score, Mbuf, nowbuf, out);
  k_idx<<<dim3(B_, 8), dim3(256), 0, stream>>>(tg, Mbuf, trans, idxbuf);
  k_btrack<<<dim3(B_), dim3(1024), 0, stream>>>(idxbuf, mask, nowbuf, out);
}

// Round 5
// 408.916 us; speedup vs baseline: 1.1536x; 1.1536x over previous
//
#include <hip/hip_runtime.h>

#define B_ 64
#define S_ 1024
#define NT 48
#define DM 512
#define TT 50

__device__ __forceinline__ float rl(float v, int lane) {
  return __int_as_float(__builtin_amdgcn_readlane(__float_as_int(v), lane));
}

// ---------------- K1: tag_vec = F @ W^T / sqrt(512) ----------------
__global__ __launch_bounds__(256) void k_tagvec(const float* __restrict__ F,
                                                const float* __restrict__ Wm,
                                                float* __restrict__ out) {
  __shared__ float fs[128][68];
  __shared__ float wsh[48][68];
  const int t = threadIdx.x;
  const int rowBase = blockIdx.x * 128;
  const int jg = t & 3;
  const int rq = t >> 2;
  const int r0 = rq * 2, r1 = r0 + 1;
  float acc0[12];
  float acc1[12];
#pragma unroll
  for (int q = 0; q < 12; ++q) { acc0[q] = 0.f; acc1[q] = 0.f; }
  for (int kc = 0; kc < DM; kc += 64) {
    __syncthreads();
#pragma unroll
    for (int i2 = 0; i2 < 8; ++i2) {
      int f = t + i2 * 256;
      int row = f >> 4, kk = f & 15;
      float4 v = *(const float4*)(F + (size_t)(rowBase + row) * DM + kc + kk * 4);
      *(float4*)&fs[row][kk * 4] = v;
    }
#pragma unroll
    for (int i2 = 0; i2 < 3; ++i2) {
      int f = t + i2 * 256;
      int row = f >> 4, kk = f & 15;
      float4 v = *(const float4*)(Wm + (size_t)row * DM + kc + kk * 4);
      *(float4*)&wsh[row][kk * 4] = v;
    }
    __syncthreads();
#pragma unroll 4
    for (int k4 = 0; k4 < 16; ++k4) {
      float4 a0 = *(const float4*)&fs[r0][k4 * 4];
      float4 a1 = *(const float4*)&fs[r1][k4 * 4];
#pragma unroll
      for (int jj = 0; jj < 12; ++jj) {
        float4 w = *(const float4*)&wsh[jg * 12 + jj][k4 * 4];
        acc0[jj] += a0.x * w.x + a0.y * w.y + a0.z * w.z + a0.w * w.w;
        acc1[jj] += a1.x * w.x + a1.y * w.y + a1.z * w.z + a1.w * w.w;
      }
    }
  }
  const float sc = 0.044194173824159216f;
  size_t base0 = (size_t)(rowBase + r0) * NT + jg * 12;
  size_t base1 = (size_t)(rowBase + r1) * NT + jg * 12;
#pragma unroll
  for (int q = 0; q < 3; ++q) {
    float4 o0 = make_float4(acc0[q*4]*sc, acc0[q*4+1]*sc, acc0[q*4+2]*sc, acc0[q*4+3]*sc);
    float4 o1 = make_float4(acc1[q*4]*sc, acc1[q*4+1]*sc, acc1[q*4+2]*sc, acc1[q*4+3]*sc);
    *(float4*)(out + base0 + q*4) = o0;
    *(float4*)(out + base1 + q*4) = o1;
  }
}

// ---------------- K2: gold-path score per batch ----------------
__global__ __launch_bounds__(256) void k_score(const float* __restrict__ tg,
                                               const int* __restrict__ y,
                                               const unsigned char* __restrict__ mask,
                                               const float* __restrict__ trans,
                                               float* __restrict__ scoreOut) {
  const int b = blockIdx.x, t = threadIdx.x;
  const int* yb = y + (size_t)b * S_;
  const unsigned char* mbp = mask + (size_t)b * S_;
  float part = 0.f;
  int cnt = 0;
  for (int s = t; s < S_; s += 256) {
    int ys = yb[s];
    int ms = mbp[s];
    float bm = ms ? 0.f : 1.f;
    int yy = ms ? 0 : ys;
    part += tg[((size_t)b * S_ + s) * NT + yy] * bm;
    if (s >= 1) part += trans[yb[s - 1] * TT + ys] * bm;
    cnt += ms ? 1 : 0;
  }
  for (int d = 1; d < 64; d <<= 1) {
    part += __shfl_xor(part, d);
    cnt += __shfl_xor(cnt, d);
  }
  __shared__ float pw[4];
  __shared__ int cw[4];
  int wid = t >> 6;
  if ((t & 63) == 0) { pw[wid] = part; cw[wid] = cnt; }
  __syncthreads();
  if (t == 0) {
    float tot = pw[0] + pw[1] + pw[2] + pw[3];
    int c = cw[0] + cw[1] + cw[2] + cw[3];
    int L = S_ - 1 - c;
    tot += trans[NT * TT + yb[0]];
    tot += trans[yb[L] * TT + (NT + 1)];
    scoreOut[b] = tot;
  }
}

// ---------------- K3: single-wave serial scans ----------------
__global__ __launch_bounds__(64, 1) void k_scan(const float* __restrict__ tg,
                                                const unsigned char* __restrict__ mask,
                                                const float* __restrict__ trans,
                                                const float* __restrict__ score,
                                                float* __restrict__ Mbuf,
                                                int* __restrict__ nowbuf,
                                                float* __restrict__ out) {
  __shared__ float bmL[S_ + 8];
  __shared__ float rbuf[256];

  const int t = threadIdx.x;
  const bool isV = blockIdx.x >= B_;
  const int b = isV ? (blockIdx.x - B_) : blockIdx.x;
  const int jc = (t < NT) ? t : (NT - 1);
  const float* tgb = tg + (size_t)b * S_ * NT;

  int cnt = 0;
  for (int m = t; m < S_; m += 64) {
    unsigned char mv = mask[(size_t)b * S_ + m];
    bmL[m] = mv ? 0.f : 1.f;
    cnt += mv ? 1 : 0;
  }
  if (t < 8) bmL[S_ + t] = 0.f;
#pragma unroll
  for (int d = 1; d < 64; d <<= 1) cnt += __shfl_xor(cnt, d);
  const int L = S_ - 1 - cnt;
  __syncthreads();

  if (!isV) {
    // ---------- forward, linear domain ----------
    float Ecol[NT];
#pragma unroll
    for (int i = 0; i < NT; ++i) Ecol[i] = __expf(trans[i * TT + jc]);
#pragma unroll
    for (int i = 0; i < NT; ++i) asm("" : "+v"(Ecol[i]));  // pin: no remat
    float p = __expf(trans[NT * TT + jc]);  // exp(start_j)
    float ebuf[8];
#pragma unroll
    for (int k = 0; k < 8; ++k) ebuf[k] = tgb[(size_t)k * NT + jc];
    float m0r = bmL[0], m1r = bmL[1];
    for (int s0 = 0; s0 < S_; s0 += 8) {
#pragma unroll
      for (int k = 0; k < 8; ++k) {
        const int s = s0 + k;
        float pe = p * __expf(ebuf[k] * m0r);
        int m1b = __builtin_amdgcn_readfirstlane(__float_as_int(m1r));
        float Z;
        if (m1b != 0) {
          float z[8];
#pragma unroll
          for (int c = 0; c < 8; ++c) z[c] = rl(pe, 6 * c) * Ecol[6 * c];
#pragma unroll
          for (int q = 1; q < 6; ++q) {
#pragma unroll
            for (int c = 0; c < 8; ++c)
              z[c] = fmaf(rl(pe, 6 * c + q), Ecol[6 * c + q], z[c]);
          }
          Z = ((z[0] + z[1]) + (z[2] + z[3])) + ((z[4] + z[5]) + (z[6] + z[7]));
        } else {
          float vv = (t < NT) ? pe : 0.f;
#pragma unroll
          for (int d = 1; d < 64; d <<= 1) vv += __shfl_xor(vv, d);
          Z = vv;
        }
        p = Z;
        if ((k & 3) == 3) {
          float M = p;
#pragma unroll
          for (int d = 1; d < 64; d <<= 1) M = fmaxf(M, __shfl_xor(M, d));
          float r = __builtin_amdgcn_rcpf(M);  // we log actual r later: exact
          p *= r;
          if (t == 0) rbuf[s >> 2] = r;
        }
        m0r = m1r;
        m1r = bmL[s + 2];
        int sp = s + 8;
        sp = (sp < S_) ? sp : (S_ - 1);
        ebuf[k] = tgb[(size_t)sp * NT + jc];
      }
    }
    float ls = 0.f;
#pragma unroll
    for (int k = 0; k < 4; ++k) ls += __logf(rbuf[t + 64 * k]);
#pragma unroll
    for (int d = 1; d < 64; d <<= 1) ls += __shfl_xor(ls, d);
    float v = (t < NT) ? p * __expf(trans[t * TT + (NT + 1)]) : 0.f;
#pragma unroll
    for (int d = 1; d < 64; d <<= 1) v += __shfl_xor(v, d);
    if (t == 0) out[b] = __logf(v) - ls - score[b];
  } else {
    // ---------- Viterbi value pass ----------
    float Tcol[NT];
#pragma unroll
    for (int i = 0; i < NT; ++i) Tcol[i] = trans[i * TT + jc];
#pragma unroll
    for (int i = 0; i < NT; ++i) asm("" : "+v"(Tcol[i]));  // pin: no remat
    float* Mb = Mbuf + (size_t)b * S_ * NT;
    float best = trans[NT * TT + jc] + tgb[jc];
    float ebuf[8];
#pragma unroll
    for (int k = 0; k < 8; ++k) ebuf[k] = tgb[(size_t)(1 + k) * NT + jc];

#define VSTEP(SS, KK, DOLOAD)                                                 \
    {                                                                         \
      float a[NT];                                                            \
      _Pragma("unroll")                                                       \
      for (int i = 0; i < NT; ++i) a[i] = rl(best, i) + Tcol[i];              \
      float m16[16];                                                          \
      _Pragma("unroll")                                                       \
      for (int q = 0; q < 16; ++q)                                            \
        m16[q] = fmaxf(fmaxf(a[3 * q], a[3 * q + 1]), a[3 * q + 2]);          \
      float r0_ = fmaxf(fmaxf(m16[0], m16[1]), m16[2]);                       \
      float r1_ = fmaxf(fmaxf(m16[3], m16[4]), m16[5]);                       \
      float r2_ = fmaxf(fmaxf(m16[6], m16[7]), m16[8]);                       \
      float r3_ = fmaxf(fmaxf(m16[9], m16[10]), m16[11]);                     \
      float r4_ = fmaxf(fmaxf(m16[12], m16[13]), m16[14]);                    \
      float f0_ = fmaxf(fmaxf(r0_, r1_), r2_);                                \
      float f1_ = fmaxf(fmaxf(r3_, r4_), m16[15]);                            \
      float M = fmaxf(f0_, f1_);                                              \
      Mb[(size_t)(SS) * NT + jc] = M;                                         \
      best = M + ebuf[KK];                                                    \
      if (DOLOAD) {                                                           \
        int sp = (SS) + 8;                                                    \
        sp = (sp < S_) ? sp : (S_ - 1);                                       \
        ebuf[KK] = tgb[(size_t)sp * NT + jc];                                 \
      }                                                                       \
    }

    for (int s0 = 1; s0 + 7 < S_; s0 += 8) {
#pragma unroll
      for (int k = 0; k < 8; ++k) {
        VSTEP(s0 + k, k, 1)
      }
    }
    // tail: s = 1017..1023 (ebuf[0..6] hold them)
#pragma unroll
    for (int k = 0; k < 7; ++k) {
      VSTEP(1017 + k, k, 0)
    }
#undef VSTEP
    // fin recovered from Mbuf (bit-exact: same operands/rounding as in-loop)
    float fin;
    if (L > 0) {
      fin = Mb[(size_t)L * NT + jc] + tgb[(size_t)L * NT + jc];
    } else {
      fin = trans[NT * TT + jc] + tgb[jc];
    }
    float v = (t < NT) ? (fin + trans[t * TT + (NT + 1)]) : -3.0e38f;
    float M = v;
#pragma unroll
    for (int d = 1; d < 64; d <<= 1) M = fmaxf(M, __shfl_xor(M, d));
    unsigned long long ball = __ballot(v == M);
    int now0 = __ffsll(ball) - 1;
    if (t == 0) nowbuf[b] = now0;
  }
}

// ---------------- K4: parallel argmax recompute (bit-exact replay) ----------------
__global__ __launch_bounds__(256) void k_idx(const float* __restrict__ tg,
                                             const float* __restrict__ Mbuf,
                                             const float* __restrict__ trans,
                                             unsigned char* __restrict__ idxbuf) {
  __shared__ float TshT[NT][NT];  // TshT[j][i] = trans[i][j]
  const int t = threadIdx.x;
  const int b = blockIdx.x;
  for (int k = t; k < NT * NT; k += 256) {
    int i = k / NT, j = k - i * NT;
    TshT[j][i] = trans[i * TT + j];
  }
  __syncthreads();
  const int s = blockIdx.y * 128 + (t >> 1);
  const int jh = (t & 1) * 24;
  if (s < 1) return;
  const float* tgb = tg + (size_t)b * S_ * NT;
  const float* Mb = Mbuf + (size_t)b * S_ * NT;
  float bprev[NT];
  if (s == 1) {
#pragma unroll
    for (int i = 0; i < NT; ++i) bprev[i] = trans[NT * TT + i] + tgb[i];
  } else {
#pragma unroll
    for (int i = 0; i < NT; ++i)
      bprev[i] = Mb[(size_t)(s - 1) * NT + i] + tgb[(size_t)(s - 1) * NT + i];
  }
  unsigned char* ob = idxbuf + ((size_t)b * S_ + s) * NT + jh;
#pragma unroll 4
  for (int jj = 0; jj < 24; ++jj) {
    int j = jh + jj;
    float M = Mb[(size_t)s * NT + j];
    int idx = 0;
#pragma unroll
    for (int i = NT - 1; i >= 0; --i) {
      float cc = bprev[i] + TshT[j][i];
      idx = (cc == M) ? i : idx;
    }
    ob[jj] = (unsigned char)idx;
  }
}

// ---------------- K5: backtrack via chunked pointer jumping ----------------
__global__ __launch_bounds__(1024) void k_btrack(const unsigned char* __restrict__ idxbuf,
                                                 const unsigned char* __restrict__ mask,
                                                 const int* __restrict__ nowbuf,
                                                 float* __restrict__ out) {
  __shared__ unsigned char idxL[S_][NT];
  __shared__ unsigned char mapc[16][NT];
  __shared__ int ELs[16];
  __shared__ int cnt_sh;
  const int t = threadIdx.x;
  const int b = blockIdx.x;
  if (t == 0) cnt_sh = 0;
  __syncthreads();
  {
    const unsigned int* src = (const unsigned int*)(idxbuf + (size_t)b * S_ * NT);
    unsigned int* dst = (unsigned int*)&idxL[t][0];
#pragma unroll
    for (int k = 0; k < 12; ++k) dst[k] = src[(size_t)t * 12 + k];
  }
  int mv = mask[(size_t)b * S_ + t] ? 1 : 0;
  unsigned long long bal = __ballot(mv);
  int wcnt = __popcll(bal);
  if ((t & 63) == 0 && wcnt) atomicAdd(&cnt_sh, wcnt);
  __syncthreads();
  const int L = S_ - 1 - cnt_sh;
  const int now0 = nowbuf[b];
  if (t < 16 * NT) {
    const int c = t / NT;
    const int g = t - c * NT;
    int cur = g;
    const int top = (c == 15) ? (S_ - 1) : (c + 1) * 64;
    const int base = c * 64;
    for (int m = top; m > base; --m) {
      if (m <= L) cur = idxL[m][cur];
    }
    mapc[c][g] = (unsigned char)cur;
  }
  __syncthreads();
  if (t == 0) {
    int e = now0;
    ELs[15] = e;
    for (int c2 = 15; c2 >= 1; --c2) {
      e = mapc[c2][e];
      ELs[c2 - 1] = e;
    }
  }
  __syncthreads();
  float* pathOut = out + B_ + (size_t)b * S_;
  if (t < 16) {
    const int c = t;
    const int top = (c == 15) ? (S_ - 1) : (c + 1) * 64;
    const int base = c * 64;
    int cu = ELs[c];
    for (int m = top; m > base; --m) {
      if (m <= L) cu = idxL[m][cu];
      int pos = m - 1;
      pathOut[pos] = (pos > L) ? -1.0f : (float)cu;
    }
  }
  if (t == 0) pathOut[S_ - 1] = (L == S_ - 1) ? (float)now0 : -1.0f;
}

extern "C" void kernel_launch(void* const* d_in, const int* in_sizes, int n_in,
                              void* d_out, int out_size, void* d_ws, size_t ws_size,
                              hipStream_t stream) {
  const float* F = (const float*)d_in[0];
  const int* y = (const int*)d_in[1];
  const unsigned char* mask = (const unsigned char*)d_in[2];
  const float* Wm = (const float*)d_in[3];
  const float* trans = (const float*)d_in[4];
  float* out = (float*)d_out;

  const size_t NTG = (size_t)B_ * S_ * NT;
  float* tg = (float*)d_ws;
  float* score = tg + NTG;
  float* Mbuf = score + 64;
  int* nowbuf = (int*)(Mbuf + NTG);
  unsigned char* idxbuf = (unsigned char*)(nowbuf + 64);

  k_tagvec<<<dim3((B_ * S_) / 128), dim3(256), 0, stream>>>(F, Wm, tg);
  k_score<<<dim3(B_), dim3(256), 0, stream>>>(tg, y, mask, trans, score);
  k_scan<<<dim3(2 * B_), dim3(64), 0, stream>>>(tg, mask, trans, score, Mbuf, nowbuf, out);
  k_idx<<<dim3(B_, 8), dim3(256), 0, stream>>>(tg, Mbuf, trans, idxbuf);
  k_btrack<<<dim3(B_), dim3(1024), 0, stream>>>(idxbuf, mask, nowbuf, out);
}